// Round 9
// baseline (165.749 us; speedup 1.0000x reference)
//
#include <hip/hip_runtime.h>

typedef __bf16 bf16_t;
typedef __bf16 bf16x8 __attribute__((ext_vector_type(8)));
typedef __bf16 bf16x4 __attribute__((ext_vector_type(4)));
typedef __bf16 bf16x2 __attribute__((ext_vector_type(2)));
typedef float  f32x4  __attribute__((ext_vector_type(4)));

#define LOG2E 1.44269504088896340736f

// ---------------- RoPE table: cos/sin [S][32] ----------------
__global__ __launch_bounds__(256) void rope_table_k(float* __restrict__ cs,
                                                    float* __restrict__ sn, int S) {
  int i = blockIdx.x * 256 + threadIdx.x;
  if (i >= S * 32) return;
  int s = i >> 5, j = i & 31;
  float theta = powf(10000.0f, -(float)j * (1.0f / 32.0f));
  float a = (float)s * theta;
  cs[i] = cosf(a);
  sn[i] = sinf(a);
}

// ---------------- fused f32 -> bf16 cast of Q,K,V ----------------
__global__ __launch_bounds__(256) void cast3_k(const float* __restrict__ A,
                                               const float* __restrict__ B,
                                               const float* __restrict__ C,
                                               bf16_t* __restrict__ oa,
                                               bf16_t* __restrict__ ob,
                                               bf16_t* __restrict__ oc) {
  const int b = blockIdx.x;
  const float* in; bf16_t* out;
  if (b < 2048) { in = A; out = oa; }
  else if (b < 4096) { in = B; out = ob; }
  else { in = C; out = oc; }
  const int j = (b & 2047) * 256 + threadIdx.x;
  const float4 v0 = *(const float4*)&in[(size_t)j * 8];
  const float4 v1 = *(const float4*)&in[(size_t)j * 8 + 4];
  bf16x8 o;
  o[0]=(bf16_t)v0.x; o[1]=(bf16_t)v0.y; o[2]=(bf16_t)v0.z; o[3]=(bf16_t)v0.w;
  o[4]=(bf16_t)v1.x; o[5]=(bf16_t)v1.y; o[6]=(bf16_t)v1.z; o[7]=(bf16_t)v1.w;
  *(bf16x8*)&out[(size_t)j * 8] = o;
}

// ---------------- fused 4x weight transpose f32(RxC) -> bf16(CxR), R=2048 ----------------
__global__ void transpose4_k(const float* __restrict__ Wq, const float* __restrict__ Wk,
                             const float* __restrict__ Wv, const float* __restrict__ Wo,
                             bf16_t* __restrict__ WqT, bf16_t* __restrict__ WkT,
                             bf16_t* __restrict__ WvT, bf16_t* __restrict__ WoT) {
  __shared__ float tile[32][33];
  const int bx = blockIdx.x;
  const float* in; bf16_t* out; int C, cbl;
  if (bx < 64)      { in = Wq; out = WqT; C = 2048; cbl = bx; }
  else if (bx < 80) { in = Wk; out = WkT; C = 512;  cbl = bx - 64; }
  else if (bx < 96) { in = Wv; out = WvT; C = 512;  cbl = bx - 80; }
  else              { in = Wo; out = WoT; C = 2048; cbl = bx - 96; }
  const int R = 2048;
  int c0 = cbl * 32, r0 = blockIdx.y * 32;
  int tx = threadIdx.x, ty = threadIdx.y;  // (32,8)
  #pragma unroll
  for (int k = 0; k < 32; k += 8)
    tile[ty + k][tx] = in[(size_t)(r0 + ty + k) * C + c0 + tx];
  __syncthreads();
  #pragma unroll
  for (int k = 0; k < 32; k += 8)
    out[(size_t)(c0 + ty + k) * R + r0 + tx] = (bf16_t)tile[tx][ty + k];
}

// XCD chunking (nb divisible by 8) + 4x4 supertile serpentine mapping
__device__ __forceinline__ int xcd_swz(int bid, int nb) {
  const int q = nb >> 3;
  return (bid & 7) * q + (bid >> 3);
}
__device__ __forceinline__ void st_map(int lin, int nstc, int& rb, int& cb) {
  const int stid = lin >> 4, w = lin & 15;
  const int sr = stid / nstc, t = stid - sr * nstc;
  const int sc = (sr & 1) ? (nstc - 1 - t) : t;
  rb = sr * 4 + (w >> 2);
  cb = sc * 4 + (w & 3);
}

// ---------------- QKV GEMM: tile 128x128, BK=64, reg prefetch, fused RoPE epilogues ----
// grid 384: cb<16 -> Q (emode0), cb<20 -> K (emode1), else V (emode2)
__global__ __launch_bounds__(256) void gemm128_k(
    const bf16_t* __restrict__ Aq, const bf16_t* __restrict__ Ak, const bf16_t* __restrict__ Av,
    const bf16_t* __restrict__ Bq, const bf16_t* __restrict__ Bk, const bf16_t* __restrict__ Bv,
    const int K, const float* __restrict__ cs, const float* __restrict__ sn,
    bf16_t* __restrict__ oq, bf16_t* __restrict__ okg, bf16_t* __restrict__ ovt, const int S) {
  __shared__ bf16_t a_lds[128][72];
  __shared__ bf16_t b_lds[128][72];
  const int tid = threadIdx.x;
  const int wid = tid >> 6, lane = tid & 63;
  const int fr = lane & 15, kg = lane >> 4;

  const int lin = xcd_swz(blockIdx.x, 384);
  int rb, cb; st_map(lin, 6, rb, cb);
  const bf16_t* Ap; const bf16_t* Bp; int emode, col0;
  if (cb < 16)      { Ap = Aq; Bp = Bq; emode = 0; col0 = cb * 128; }
  else if (cb < 20) { Ap = Ak; Bp = Bk; emode = 1; col0 = (cb - 16) * 128; }
  else              { Ap = Av; Bp = Bv; emode = 2; col0 = (cb - 20) * 128; }
  const int row0 = rb * 128;
  const int wr = (wid >> 1) * 64, wc = (wid & 1) * 64;

  f32x4 acc[4][4];
  #pragma unroll
  for (int i = 0; i < 4; ++i)
    #pragma unroll
    for (int j = 0; j < 4; ++j)
      acc[i][j] = (f32x4){0.f, 0.f, 0.f, 0.f};

  // staging: 128 rows, 2 threads/row, 32 elems (4 x bf16x8) each
  const int rw = tid >> 1, sg = (tid & 1) * 32;
  bf16x8 a0, a1, a2, a3, b0, b1, b2, b3;

#define LOADG(kt)                                                              \
  do {                                                                         \
    const bf16_t* p = &Ap[(size_t)(row0 + rw) * K + (kt) + sg];                \
    a0 = *(const bf16x8*)(p);      a1 = *(const bf16x8*)(p + 8);               \
    a2 = *(const bf16x8*)(p + 16); a3 = *(const bf16x8*)(p + 24);              \
    const bf16_t* q2 = &Bp[(size_t)(col0 + rw) * K + (kt) + sg];               \
    b0 = *(const bf16x8*)(q2);      b1 = *(const bf16x8*)(q2 + 8);             \
    b2 = *(const bf16x8*)(q2 + 16); b3 = *(const bf16x8*)(q2 + 24);            \
  } while (0)

  LOADG(0);

  for (int kt = 0; kt < K; kt += 64) {
    __syncthreads();
    *(bf16x8*)&a_lds[rw][sg]      = a0;
    *(bf16x8*)&a_lds[rw][sg + 8]  = a1;
    *(bf16x8*)&a_lds[rw][sg + 16] = a2;
    *(bf16x8*)&a_lds[rw][sg + 24] = a3;
    *(bf16x8*)&b_lds[rw][sg]      = b0;
    *(bf16x8*)&b_lds[rw][sg + 8]  = b1;
    *(bf16x8*)&b_lds[rw][sg + 16] = b2;
    *(bf16x8*)&b_lds[rw][sg + 24] = b3;
    __syncthreads();
    if (kt + 64 < K) LOADG(kt + 64);  // prefetch next K-step; lands during MFMA
    #pragma unroll
    for (int ks = 0; ks < 2; ++ks) {
      bf16x8 af[4], bfr[4];
      #pragma unroll
      for (int mi = 0; mi < 4; ++mi) af[mi]  = *(const bf16x8*)&a_lds[wr + mi * 16 + fr][ks * 32 + kg * 8];
      #pragma unroll
      for (int ni = 0; ni < 4; ++ni) bfr[ni] = *(const bf16x8*)&b_lds[wc + ni * 16 + fr][ks * 32 + kg * 8];
      #pragma unroll
      for (int mi = 0; mi < 4; ++mi)
        #pragma unroll
        for (int ni = 0; ni < 4; ++ni)
          acc[mi][ni] = __builtin_amdgcn_mfma_f32_16x16x32_bf16(af[mi], bfr[ni], acc[mi][ni], 0, 0, 0);
    }
  }
#undef LOADG

  #pragma unroll
  for (int mi = 0; mi < 4; ++mi) {
    #pragma unroll
    for (int ni = 0; ni < 4; ++ni) {
      #pragma unroll
      for (int r = 0; r < 4; ++r) {
        const int grow = row0 + wr + mi * 16 + kg * 4 + r;  // C row = 4*(lane>>4)+reg
        const int gcol = col0 + wc + ni * 16 + fr;          // C col = lane&15
        float v = acc[mi][ni][r];
        if (emode == 2) {
          const int gi = gcol >> 6, d = gcol & 63;
          ovt[((size_t)gi * 64 + d) * S + grow] = (bf16_t)v;
        } else {
          const float pv = __shfl_xor(v, 1);  // RoPE partner (d^1), same row
          const int d = gcol & 63, p = d >> 1, hh = gcol >> 6;
          const float c = cs[grow * 32 + p], s = sn[grow * 32 + p];
          float o = (d & 1) ? fmaf(pv, s, v * c) : fmaf(-pv, s, v * c);
          if (emode == 0) {
            o *= 0.125f * LOG2E;  // fold 1/sqrt(64) and log2(e) into q
            oq[((size_t)hh * S + grow) * 64 + d] = (bf16_t)o;
          } else {
            okg[((size_t)hh * S + grow) * 64 + d] = (bf16_t)o;
          }
        }
      }
    }
  }
}

// ---------------- O-proj GEMM: tile 64x128, BK=64, reg prefetch, +bias f32 store ----
__global__ __launch_bounds__(256) void gemm64o_k(
    const bf16_t* __restrict__ A, const bf16_t* __restrict__ BT,
    const int K, const int N,
    float* __restrict__ ofp, const float* __restrict__ bias) {
  __shared__ bf16_t a_lds[64][72];
  __shared__ bf16_t b_lds[128][72];
  const int tid = threadIdx.x;
  const int wid = tid >> 6, lane = tid & 63;
  const int fr = lane & 15, kg = lane >> 4;

  const int lin = xcd_swz(blockIdx.x, 512);
  int rb, cb; st_map(lin, 4, rb, cb);
  const int row0 = rb * 64, col0 = cb * 128;
  const int wr = (wid >> 1) * 32, wc = (wid & 1) * 64;

  f32x4 acc[2][4];
  #pragma unroll
  for (int i = 0; i < 2; ++i)
    #pragma unroll
    for (int j = 0; j < 4; ++j)
      acc[i][j] = (f32x4){0.f, 0.f, 0.f, 0.f};

  const int ra = tid >> 2, sa = (tid & 3) * 16;
  const int rbv = tid >> 1, sb = (tid & 1) * 32;
  bf16x8 a0, a1, b0, b1, b2, b3;

#define LOADG(kt)                                                              \
  do {                                                                         \
    const bf16_t* p = &A[(size_t)(row0 + ra) * K + (kt) + sa];                 \
    a0 = *(const bf16x8*)(p); a1 = *(const bf16x8*)(p + 8);                    \
    const bf16_t* q2 = &BT[(size_t)(col0 + rbv) * K + (kt) + sb];              \
    b0 = *(const bf16x8*)(q2);      b1 = *(const bf16x8*)(q2 + 8);             \
    b2 = *(const bf16x8*)(q2 + 16); b3 = *(const bf16x8*)(q2 + 24);            \
  } while (0)

  LOADG(0);

  for (int kt = 0; kt < K; kt += 64) {
    __syncthreads();
    *(bf16x8*)&a_lds[ra][sa]      = a0;
    *(bf16x8*)&a_lds[ra][sa + 8]  = a1;
    *(bf16x8*)&b_lds[rbv][sb]      = b0;
    *(bf16x8*)&b_lds[rbv][sb + 8]  = b1;
    *(bf16x8*)&b_lds[rbv][sb + 16] = b2;
    *(bf16x8*)&b_lds[rbv][sb + 24] = b3;
    __syncthreads();
    if (kt + 64 < K) LOADG(kt + 64);
    #pragma unroll
    for (int ks = 0; ks < 2; ++ks) {
      bf16x8 af[2], bfr[4];
      #pragma unroll
      for (int mi = 0; mi < 2; ++mi) af[mi]  = *(const bf16x8*)&a_lds[wr + mi * 16 + fr][ks * 32 + kg * 8];
      #pragma unroll
      for (int ni = 0; ni < 4; ++ni) bfr[ni] = *(const bf16x8*)&b_lds[wc + ni * 16 + fr][ks * 32 + kg * 8];
      #pragma unroll
      for (int mi = 0; mi < 2; ++mi)
        #pragma unroll
        for (int ni = 0; ni < 4; ++ni)
          acc[mi][ni] = __builtin_amdgcn_mfma_f32_16x16x32_bf16(af[mi], bfr[ni], acc[mi][ni], 0, 0, 0);
    }
  }
#undef LOADG

  #pragma unroll
  for (int mi = 0; mi < 2; ++mi) {
    #pragma unroll
    for (int ni = 0; ni < 4; ++ni) {
      #pragma unroll
      for (int r = 0; r < 4; ++r) {
        const int grow = row0 + wr + mi * 16 + kg * 4 + r;
        const int gcol = col0 + wc + ni * 16 + fr;
        ofp[(size_t)grow * N + gcol] = acc[mi][ni][r] + bias[gcol];
      }
    }
  }
}

// XOR-swizzled LDS index (T2): row stride 64 bf16 (128B), 16B chunk c^(row&7).
__device__ __forceinline__ int swz8(int r, int c) { return r * 64 + (((c) ^ (r & 7)) << 3); }

// ---------------- flash attention v3: single-buf + XOR swizzle + true LPT ----------------
__global__ __launch_bounds__(256) void attn_k(
    const bf16_t* __restrict__ qh,   // [32][S][64], pre-scaled by 0.125*log2e
    const bf16_t* __restrict__ kgr,  // [8][S][64]
    const bf16_t* __restrict__ vtg,  // [8][64][S]
    const int* __restrict__ amask,   // [S]
    bf16_t* __restrict__ ao,         // [S][2048]
    const int S) {
  __shared__ bf16_t k_lds[64 * 64];
  __shared__ bf16_t vt_lds[64 * 64];
  __shared__ bf16_t p_lds[4][16 * 64];
  const int tid = threadIdx.x, wid = tid >> 6, lane = tid & 63;
  const int fr = lane & 15, kgp = lane >> 4;
  const int h = blockIdx.x, g = h >> 2;
  const int qb = 31 - blockIdx.y;      // LPT: heavy blocks first in dispatch order
  const int q0 = qb * 64 + wid * 16;
  const int qg = q0 + fr;

  const bf16_t* qbase = qh + ((size_t)h * S + q0 + fr) * 64;
  const bf16x8 qf0 = *(const bf16x8*)&qbase[kgp * 8];
  const bf16x8 qf1 = *(const bf16x8*)&qbase[32 + kgp * 8];

  f32x4 oacc[4];
  #pragma unroll
  for (int t = 0; t < 4; ++t) oacc[t] = (f32x4){0.f, 0.f, 0.f, 0.f};
  float m_ = -1e30f, l_ = 0.f;

  const int srow = tid >> 2, sc4 = tid & 3;
  const bf16_t* kbase = kgr + (size_t)g * S * 64;
  const bf16_t* vbase = vtg + (size_t)g * 64 * S;
  const int cmax = qb + 1;

  bf16x8 nk0 = *(const bf16x8*)&kbase[(size_t)srow * 64 + sc4 * 8];
  bf16x8 nk1 = *(const bf16x8*)&kbase[(size_t)srow * 64 + 32 + sc4 * 8];
  bf16x8 nv0 = *(const bf16x8*)&vbase[(size_t)srow * S + sc4 * 8];
  bf16x8 nv1 = *(const bf16x8*)&vbase[(size_t)srow * S + 32 + sc4 * 8];
  int mvc = amask[lane];
  *(bf16x8*)&k_lds[swz8(srow, sc4)]      = nk0;
  *(bf16x8*)&k_lds[swz8(srow, 4 + sc4)]  = nk1;
  *(bf16x8*)&vt_lds[swz8(srow, sc4)]     = nv0;
  *(bf16x8*)&vt_lds[swz8(srow, 4 + sc4)] = nv1;
  __syncthreads();

  for (int c = 0; c < cmax; ++c) {
    const int kc0 = c * 64;
    const unsigned long long pm = __ballot(mvc == 0);
    const bool more = (c + 1 < cmax);
    if (more) {  // issue-early prefetch (written after compute)
      const int kc1 = kc0 + 64;
      nk0 = *(const bf16x8*)&kbase[(size_t)(kc1 + srow) * 64 + sc4 * 8];
      nk1 = *(const bf16x8*)&kbase[(size_t)(kc1 + srow) * 64 + 32 + sc4 * 8];
      nv0 = *(const bf16x8*)&vbase[(size_t)srow * S + kc1 + sc4 * 8];
      nv1 = *(const bf16x8*)&vbase[(size_t)srow * S + kc1 + 32 + sc4 * 8];
      mvc = amask[kc1 + lane];
    }

    f32x4 sc[4];
    #pragma unroll
    for (int a = 0; a < 4; ++a) {
      const bf16x8 ka0 = *(const bf16x8*)&k_lds[swz8(a * 16 + fr, kgp)];
      const bf16x8 ka1 = *(const bf16x8*)&k_lds[swz8(a * 16 + fr, 4 + kgp)];
      f32x4 z = (f32x4){0.f, 0.f, 0.f, 0.f};
      z = __builtin_amdgcn_mfma_f32_16x16x32_bf16(ka0, qf0, z, 0, 0, 0);
      z = __builtin_amdgcn_mfma_f32_16x16x32_bf16(ka1, qf1, z, 0, 0, 0);
      sc[a] = z;
    }

    if (c == qb) {
      #pragma unroll
      for (int a = 0; a < 4; ++a)
        #pragma unroll
        for (int r = 0; r < 4; ++r) {
          const int kl = a * 16 + 4 * kgp + r;
          if (kc0 + kl > qg) sc[a][r] = -1e30f;
        }
    }
    if (pm) {
      #pragma unroll
      for (int a = 0; a < 4; ++a)
        #pragma unroll
        for (int r = 0; r < 4; ++r) {
          const int kl = a * 16 + 4 * kgp + r;
          if ((pm >> kl) & 1) sc[a][r] = -1e30f;
        }
    }

    float smax = sc[0][0];
    #pragma unroll
    for (int a = 0; a < 4; ++a)
      #pragma unroll
      for (int r = 0; r < 4; ++r) smax = fmaxf(smax, sc[a][r]);
    smax = fmaxf(smax, __shfl_xor(smax, 16));
    smax = fmaxf(smax, __shfl_xor(smax, 32));
    const float mn = fmaxf(m_, smax);
    const float al = exp2f(m_ - mn);
    float ps = 0.f;
    #pragma unroll
    for (int a = 0; a < 4; ++a)
      #pragma unroll
      for (int r = 0; r < 4; ++r) {
        const float p = exp2f(sc[a][r] - mn);
        sc[a][r] = p;
        ps += p;
      }
    ps += __shfl_xor(ps, 16);
    ps += __shfl_xor(ps, 32);
    l_ = l_ * al + ps;
    m_ = mn;
    #pragma unroll
    for (int t = 0; t < 4; ++t)
      #pragma unroll
      for (int r = 0; r < 4; ++r) oacc[t][r] *= al;

    #pragma unroll
    for (int a = 0; a < 4; ++a)
      #pragma unroll
      for (int j = 0; j < 2; ++j) {
        bf16x2 w;
        w[0] = (bf16_t)sc[a][2 * j];
        w[1] = (bf16_t)sc[a][2 * j + 1];
        const int off = a * 16 + 4 * kgp + 2 * j;
        *(bf16x2*)&p_lds[wid][fr * 64 + (((off >> 3) ^ (fr & 7)) << 3) + (off & 7)] = w;
      }
    const bf16x8 pa0 = *(const bf16x8*)&p_lds[wid][swz8(fr, kgp)];
    const bf16x8 pa1 = *(const bf16x8*)&p_lds[wid][swz8(fr, 4 + kgp)];

    #pragma unroll
    for (int t = 0; t < 4; ++t) {
      const bf16x8 vb0 = *(const bf16x8*)&vt_lds[swz8(t * 16 + fr, kgp)];
      const bf16x8 vb1 = *(const bf16x8*)&vt_lds[swz8(t * 16 + fr, 4 + kgp)];
      oacc[t] = __builtin_amdgcn_mfma_f32_16x16x32_bf16(vb0, pa0, oacc[t], 0, 0, 0);
      oacc[t] = __builtin_amdgcn_mfma_f32_16x16x32_bf16(vb1, pa1, oacc[t], 0, 0, 0);
    }

    if (more) {
      __syncthreads();
      *(bf16x8*)&k_lds[swz8(srow, sc4)]      = nk0;
      *(bf16x8*)&k_lds[swz8(srow, 4 + sc4)]  = nk1;
      *(bf16x8*)&vt_lds[swz8(srow, sc4)]     = nv0;
      *(bf16x8*)&vt_lds[swz8(srow, 4 + sc4)] = nv1;
      __syncthreads();
    }
  }

  const float inv = 1.0f / l_;
  #pragma unroll
  for (int t = 0; t < 4; ++t) {
    bf16x4 o4;
    #pragma unroll
    for (int r = 0; r < 4; ++r) o4[r] = (bf16_t)(oacc[t][r] * inv);
    *(bf16x4*)&ao[(size_t)(q0 + fr) * 2048 + h * 64 + t * 16 + 4 * kgp] = o4;
  }
}

// ---------------- launcher ----------------
extern "C" void kernel_launch(void* const* d_in, const int* in_sizes, int n_in,
                              void* d_out, int out_size, void* d_ws, size_t ws_size,
                              hipStream_t stream) {
  const float* Q  = (const float*)d_in[0];
  const float* K  = (const float*)d_in[1];
  const float* V  = (const float*)d_in[2];
  const int*   am = (const int*)d_in[3];
  const float* Wq = (const float*)d_in[4];
  const float* Wk = (const float*)d_in[5];
  const float* Wv = (const float*)d_in[6];
  const float* Wo = (const float*)d_in[7];
  const float* bo = (const float*)d_in[8];
  float* out = (float*)d_out;

  const int S = 2048, D = 2048;
  char* w = (char*)d_ws;
  const size_t MB = 1u << 20;
  bf16_t* WqT = (bf16_t*)(w + 0 * MB);   // [D][D]
  bf16_t* WoT = (bf16_t*)(w + 8 * MB);   // [D][D]
  bf16_t* WkT = (bf16_t*)(w + 16 * MB);  // [KV][D]
  bf16_t* WvT = (bf16_t*)(w + 18 * MB);
  bf16_t* qh  = (bf16_t*)(w + 20 * MB);  // [32][S][64]
  bf16_t* kgr = (bf16_t*)(w + 28 * MB);  // [8][S][64]
  bf16_t* vtg = (bf16_t*)(w + 30 * MB);  // [8][64][S]
  bf16_t* ao  = (bf16_t*)(w + 32 * MB);  // [S][D]
  bf16_t* Qb  = (bf16_t*)(w + 40 * MB);  // [S][D] bf16
  bf16_t* Kb  = (bf16_t*)(w + 48 * MB);
  bf16_t* Vb  = (bf16_t*)(w + 56 * MB);
  float*  cs  = (float*)(w + 64 * MB);   // [S][32]
  float*  sn  = (float*)(w + 64 * MB + 256 * 1024);

  rope_table_k<<<256, 256, 0, stream>>>(cs, sn, S);
  cast3_k<<<6144, 256, 0, stream>>>(Q, K, V, Qb, Kb, Vb);
  transpose4_k<<<dim3(160, 64), dim3(32, 8), 0, stream>>>(Wq, Wk, Wv, Wo, WqT, WkT, WvT, WoT);

  // fused Q+K+V projections: 384 blocks (128x128 tiles), XCD + supertile swizzle
  gemm128_k<<<384, 256, 0, stream>>>(Qb, Kb, Vb, WqT, WkT, WvT, D,
                                     cs, sn, qh, kgr, vtg, S);

  attn_k<<<dim3(32, 32), 256, 0, stream>>>(qh, kgr, vtg, am, ao, S);

  // O-proj: 512 blocks (64x128 tiles), XCD + supertile swizzle
  gemm64o_k<<<512, 256, 0, stream>>>(ao, WoT, D, D, out, bo);
}

// Round 10
// 153.538 us; speedup vs baseline: 1.0795x; 1.0795x over previous
//
#include <hip/hip_runtime.h>

typedef __bf16 bf16_t;
typedef __bf16 bf16x8 __attribute__((ext_vector_type(8)));
typedef __bf16 bf16x4 __attribute__((ext_vector_type(4)));
typedef __bf16 bf16x2 __attribute__((ext_vector_type(2)));
typedef float  f32x4  __attribute__((ext_vector_type(4)));

#define LOG2E 1.44269504088896340736f

// global -> LDS direct (width 16B). LDS dest is wave-uniform base + lane*16.
#define GLDS(gp, lp)                                                           \
  __builtin_amdgcn_global_load_lds(                                            \
      (const __attribute__((address_space(1))) void*)(gp),                     \
      (__attribute__((address_space(3))) void*)(lp), 16, 0, 0)

// ---------------- RoPE table: cos/sin [S][32] ----------------
__global__ __launch_bounds__(256) void rope_table_k(float* __restrict__ cs,
                                                    float* __restrict__ sn, int S) {
  int i = blockIdx.x * 256 + threadIdx.x;
  if (i >= S * 32) return;
  int s = i >> 5, j = i & 31;
  float theta = powf(10000.0f, -(float)j * (1.0f / 32.0f));
  float a = (float)s * theta;
  cs[i] = cosf(a);
  sn[i] = sinf(a);
}

// ---------------- fused f32 -> bf16 cast of Q,K,V ----------------
__global__ __launch_bounds__(256) void cast3_k(const float* __restrict__ A,
                                               const float* __restrict__ B,
                                               const float* __restrict__ C,
                                               bf16_t* __restrict__ oa,
                                               bf16_t* __restrict__ ob,
                                               bf16_t* __restrict__ oc) {
  const int b = blockIdx.x;
  const float* in; bf16_t* out;
  if (b < 2048) { in = A; out = oa; }
  else if (b < 4096) { in = B; out = ob; }
  else { in = C; out = oc; }
  const int j = (b & 2047) * 256 + threadIdx.x;
  const float4 v0 = *(const float4*)&in[(size_t)j * 8];
  const float4 v1 = *(const float4*)&in[(size_t)j * 8 + 4];
  bf16x8 o;
  o[0]=(bf16_t)v0.x; o[1]=(bf16_t)v0.y; o[2]=(bf16_t)v0.z; o[3]=(bf16_t)v0.w;
  o[4]=(bf16_t)v1.x; o[5]=(bf16_t)v1.y; o[6]=(bf16_t)v1.z; o[7]=(bf16_t)v1.w;
  *(bf16x8*)&out[(size_t)j * 8] = o;
}

// ---------------- fused 4x weight transpose f32(RxC) -> bf16(CxR), R=2048 ----------------
__global__ void transpose4_k(const float* __restrict__ Wq, const float* __restrict__ Wk,
                             const float* __restrict__ Wv, const float* __restrict__ Wo,
                             bf16_t* __restrict__ WqT, bf16_t* __restrict__ WkT,
                             bf16_t* __restrict__ WvT, bf16_t* __restrict__ WoT) {
  __shared__ float tile[32][33];
  const int bx = blockIdx.x;
  const float* in; bf16_t* out; int C, cbl;
  if (bx < 64)      { in = Wq; out = WqT; C = 2048; cbl = bx; }
  else if (bx < 80) { in = Wk; out = WkT; C = 512;  cbl = bx - 64; }
  else if (bx < 96) { in = Wv; out = WvT; C = 512;  cbl = bx - 80; }
  else              { in = Wo; out = WoT; C = 2048; cbl = bx - 96; }
  const int R = 2048;
  int c0 = cbl * 32, r0 = blockIdx.y * 32;
  int tx = threadIdx.x, ty = threadIdx.y;  // (32,8)
  #pragma unroll
  for (int k = 0; k < 32; k += 8)
    tile[ty + k][tx] = in[(size_t)(r0 + ty + k) * C + c0 + tx];
  __syncthreads();
  #pragma unroll
  for (int k = 0; k < 32; k += 8)
    out[(size_t)(c0 + ty + k) * R + r0 + tx] = (bf16_t)tile[tx][ty + k];
}

// XCD chunking (nb divisible by 8) + 4x4 supertile serpentine mapping
__device__ __forceinline__ int xcd_swz(int bid, int nb) {
  const int q = nb >> 3;
  return (bid & 7) * q + (bid >> 3);
}
__device__ __forceinline__ void st_map(int lin, int nstc, int& rb, int& cb) {
  const int stid = lin >> 4, w = lin & 15;
  const int sr = stid / nstc, t = stid - sr * nstc;
  const int sc = (sr & 1) ? (nstc - 1 - t) : t;
  rb = sr * 4 + (w >> 2);
  cb = sc * 4 + (w & 3);
}

// ---------------- GEMM via global_load_lds: tile 64(M)x128(N), BK=64 ----------------
// Linear LDS rows of 64 bf16 (128B); source pre-swizzled by chunk^(row&7); reads
// apply the same XOR -> 2-way bank aliasing (free). 6 load-instr/wave/K-step.
// MODE 0 (QKV, 768 blocks): cb<16 Q->RoPE-scaled qh; cb<20 K->RoPE kgr; else V->vT vtg
// MODE 1 (O-proj, 512 blocks): f32 out + bias
template<int MODE>
__global__ __launch_bounds__(256) void gemm_glds_k(
    const bf16_t* __restrict__ Aq, const bf16_t* __restrict__ Ak, const bf16_t* __restrict__ Av,
    const bf16_t* __restrict__ Bq, const bf16_t* __restrict__ Bk, const bf16_t* __restrict__ Bv,
    const int K, const float* __restrict__ cs, const float* __restrict__ sn,
    bf16_t* __restrict__ oq, bf16_t* __restrict__ okg, bf16_t* __restrict__ ovt,
    float* __restrict__ ofp, const float* __restrict__ bias, const int S) {
  __shared__ bf16_t a_lds[64 * 64];    // 8 KB, linear
  __shared__ bf16_t b_lds[128 * 64];   // 16 KB, linear
  const int tid = threadIdx.x, wid = tid >> 6, lane = tid & 63;
  const int fr = lane & 15, kg = lane >> 4;

  constexpr int NB   = (MODE == 0) ? 768 : 512;
  constexpr int NSTC = (MODE == 0) ? 6 : 4;
  const int lin = xcd_swz(blockIdx.x, NB);
  int rb, cb; st_map(lin, NSTC, rb, cb);
  const bf16_t* Ap; const bf16_t* Bp; int emode, col0;
  if (MODE == 1)    { Ap = Aq; Bp = Bq; emode = 3; col0 = cb * 128; }
  else if (cb < 16) { Ap = Aq; Bp = Bq; emode = 0; col0 = cb * 128; }
  else if (cb < 20) { Ap = Ak; Bp = Bk; emode = 1; col0 = (cb - 16) * 128; }
  else              { Ap = Av; Bp = Bv; emode = 2; col0 = (cb - 20) * 128; }
  const int row0 = rb * 64;
  const int wr = (wid >> 1) * 32, wc = (wid & 1) * 64;

  f32x4 acc[2][4];
  #pragma unroll
  for (int i = 0; i < 2; ++i)
    #pragma unroll
    for (int j = 0; j < 4; ++j)
      acc[i][j] = (f32x4){0.f, 0.f, 0.f, 0.f};

  // staging geometry: each wave-instr covers 8 rows x 128B contiguous LDS.
  // lane l -> row sub*8 + (l>>3), LDS chunk l&7; source chunk (l&7)^(row&7).
  const int rloc = lane >> 3;                  // 0..7
  const int schunk = ((lane & 7) ^ rloc) * 8;  // pre-swizzled source elem offset
  const bf16_t* gA0 = Ap + (size_t)(row0 + (wid * 2 + 0) * 8 + rloc) * K + schunk;
  const bf16_t* gA1 = Ap + (size_t)(row0 + (wid * 2 + 1) * 8 + rloc) * K + schunk;
  const bf16_t* gB0 = Bp + (size_t)(col0 + (wid * 4 + 0) * 8 + rloc) * K + schunk;
  const bf16_t* gB1 = Bp + (size_t)(col0 + (wid * 4 + 1) * 8 + rloc) * K + schunk;
  const bf16_t* gB2 = Bp + (size_t)(col0 + (wid * 4 + 2) * 8 + rloc) * K + schunk;
  const bf16_t* gB3 = Bp + (size_t)(col0 + (wid * 4 + 3) * 8 + rloc) * K + schunk;
  bf16_t* lA0 = &a_lds[(wid * 2 + 0) * 512];   // wave-uniform LDS bases
  bf16_t* lA1 = &a_lds[(wid * 2 + 1) * 512];
  bf16_t* lB0 = &b_lds[(wid * 4 + 0) * 512];
  bf16_t* lB1 = &b_lds[(wid * 4 + 1) * 512];
  bf16_t* lB2 = &b_lds[(wid * 4 + 2) * 512];
  bf16_t* lB3 = &b_lds[(wid * 4 + 3) * 512];

  for (int kt = 0; kt < K; kt += 64) {
    __syncthreads();                 // all waves done reading previous tile
    GLDS(gA0 + kt, lA0);
    GLDS(gA1 + kt, lA1);
    GLDS(gB0 + kt, lB0);
    GLDS(gB1 + kt, lB1);
    GLDS(gB2 + kt, lB2);
    GLDS(gB3 + kt, lB3);
    __syncthreads();                 // compiler drains vmcnt(0) before barrier
    #pragma unroll
    for (int ks = 0; ks < 2; ++ks) {
      bf16x8 af[2], bfr[4];
      #pragma unroll
      for (int mi = 0; mi < 2; ++mi) {
        const int r = wr + mi * 16 + fr;
        af[mi] = *(const bf16x8*)&a_lds[r * 64 + (((ks * 4 + kg) ^ (fr & 7)) * 8)];
      }
      #pragma unroll
      for (int ni = 0; ni < 4; ++ni) {
        const int r = wc + ni * 16 + fr;
        bfr[ni] = *(const bf16x8*)&b_lds[r * 64 + (((ks * 4 + kg) ^ (fr & 7)) * 8)];
      }
      #pragma unroll
      for (int mi = 0; mi < 2; ++mi)
        #pragma unroll
        for (int ni = 0; ni < 4; ++ni)
          acc[mi][ni] = __builtin_amdgcn_mfma_f32_16x16x32_bf16(af[mi], bfr[ni], acc[mi][ni], 0, 0, 0);
    }
  }

  #pragma unroll
  for (int mi = 0; mi < 2; ++mi) {
    #pragma unroll
    for (int ni = 0; ni < 4; ++ni) {
      #pragma unroll
      for (int r = 0; r < 4; ++r) {
        const int grow = row0 + wr + mi * 16 + kg * 4 + r;  // C row = 4*(lane>>4)+reg
        const int gcol = col0 + wc + ni * 16 + fr;          // C col = lane&15
        float v = acc[mi][ni][r];
        if (emode == 3) {
          ofp[(size_t)grow * 2048 + gcol] = v + bias[gcol];
        } else if (emode == 2) {
          const int gi = gcol >> 6, d = gcol & 63;
          ovt[((size_t)gi * 64 + d) * S + grow] = (bf16_t)v;
        } else {
          const float pv = __shfl_xor(v, 1);  // RoPE partner (d^1), same row
          const int d = gcol & 63, p = d >> 1, hh = gcol >> 6;
          const float c = cs[grow * 32 + p], s = sn[grow * 32 + p];
          float o = (d & 1) ? fmaf(pv, s, v * c) : fmaf(-pv, s, v * c);
          if (emode == 0) {
            o *= 0.125f * LOG2E;  // fold 1/sqrt(64) and log2(e) into q
            oq[((size_t)hh * S + grow) * 64 + d] = (bf16_t)o;
          } else {
            okg[((size_t)hh * S + grow) * 64 + d] = (bf16_t)o;
          }
        }
      }
    }
  }
}

// XOR-swizzled LDS index (T2): row stride 64 bf16 (128B), 16B chunk c^(row&7).
__device__ __forceinline__ int swz8(int r, int c) { return r * 64 + (((c) ^ (r & 7)) << 3); }

// ---------------- flash attention v3: single-buf + XOR swizzle + true LPT ----------------
__global__ __launch_bounds__(256) void attn_k(
    const bf16_t* __restrict__ qh,   // [32][S][64], pre-scaled by 0.125*log2e
    const bf16_t* __restrict__ kgr,  // [8][S][64]
    const bf16_t* __restrict__ vtg,  // [8][64][S]
    const int* __restrict__ amask,   // [S]
    bf16_t* __restrict__ ao,         // [S][2048]
    const int S) {
  __shared__ bf16_t k_lds[64 * 64];
  __shared__ bf16_t vt_lds[64 * 64];
  __shared__ bf16_t p_lds[4][16 * 64];
  const int tid = threadIdx.x, wid = tid >> 6, lane = tid & 63;
  const int fr = lane & 15, kgp = lane >> 4;
  const int h = blockIdx.x, g = h >> 2;
  const int qb = 31 - blockIdx.y;      // LPT: heavy blocks first in dispatch order
  const int q0 = qb * 64 + wid * 16;
  const int qg = q0 + fr;

  const bf16_t* qbase = qh + ((size_t)h * S + q0 + fr) * 64;
  const bf16x8 qf0 = *(const bf16x8*)&qbase[kgp * 8];
  const bf16x8 qf1 = *(const bf16x8*)&qbase[32 + kgp * 8];

  f32x4 oacc[4];
  #pragma unroll
  for (int t = 0; t < 4; ++t) oacc[t] = (f32x4){0.f, 0.f, 0.f, 0.f};
  float m_ = -1e30f, l_ = 0.f;

  const int srow = tid >> 2, sc4 = tid & 3;
  const bf16_t* kbase = kgr + (size_t)g * S * 64;
  const bf16_t* vbase = vtg + (size_t)g * 64 * S;
  const int cmax = qb + 1;

  bf16x8 nk0 = *(const bf16x8*)&kbase[(size_t)srow * 64 + sc4 * 8];
  bf16x8 nk1 = *(const bf16x8*)&kbase[(size_t)srow * 64 + 32 + sc4 * 8];
  bf16x8 nv0 = *(const bf16x8*)&vbase[(size_t)srow * S + sc4 * 8];
  bf16x8 nv1 = *(const bf16x8*)&vbase[(size_t)srow * S + 32 + sc4 * 8];
  int mvc = amask[lane];
  *(bf16x8*)&k_lds[swz8(srow, sc4)]      = nk0;
  *(bf16x8*)&k_lds[swz8(srow, 4 + sc4)]  = nk1;
  *(bf16x8*)&vt_lds[swz8(srow, sc4)]     = nv0;
  *(bf16x8*)&vt_lds[swz8(srow, 4 + sc4)] = nv1;
  __syncthreads();

  for (int c = 0; c < cmax; ++c) {
    const int kc0 = c * 64;
    const unsigned long long pm = __ballot(mvc == 0);
    const bool more = (c + 1 < cmax);
    if (more) {  // issue-early prefetch (written after compute)
      const int kc1 = kc0 + 64;
      nk0 = *(const bf16x8*)&kbase[(size_t)(kc1 + srow) * 64 + sc4 * 8];
      nk1 = *(const bf16x8*)&kbase[(size_t)(kc1 + srow) * 64 + 32 + sc4 * 8];
      nv0 = *(const bf16x8*)&vbase[(size_t)srow * S + kc1 + sc4 * 8];
      nv1 = *(const bf16x8*)&vbase[(size_t)srow * S + kc1 + 32 + sc4 * 8];
      mvc = amask[kc1 + lane];
    }

    f32x4 sc[4];
    #pragma unroll
    for (int a = 0; a < 4; ++a) {
      const bf16x8 ka0 = *(const bf16x8*)&k_lds[swz8(a * 16 + fr, kgp)];
      const bf16x8 ka1 = *(const bf16x8*)&k_lds[swz8(a * 16 + fr, 4 + kgp)];
      f32x4 z = (f32x4){0.f, 0.f, 0.f, 0.f};
      z = __builtin_amdgcn_mfma_f32_16x16x32_bf16(ka0, qf0, z, 0, 0, 0);
      z = __builtin_amdgcn_mfma_f32_16x16x32_bf16(ka1, qf1, z, 0, 0, 0);
      sc[a] = z;
    }

    if (c == qb) {
      #pragma unroll
      for (int a = 0; a < 4; ++a)
        #pragma unroll
        for (int r = 0; r < 4; ++r) {
          const int kl = a * 16 + 4 * kgp + r;
          if (kc0 + kl > qg) sc[a][r] = -1e30f;
        }
    }
    if (pm) {
      #pragma unroll
      for (int a = 0; a < 4; ++a)
        #pragma unroll
        for (int r = 0; r < 4; ++r) {
          const int kl = a * 16 + 4 * kgp + r;
          if ((pm >> kl) & 1) sc[a][r] = -1e30f;
        }
    }

    float smax = sc[0][0];
    #pragma unroll
    for (int a = 0; a < 4; ++a)
      #pragma unroll
      for (int r = 0; r < 4; ++r) smax = fmaxf(smax, sc[a][r]);
    smax = fmaxf(smax, __shfl_xor(smax, 16));
    smax = fmaxf(smax, __shfl_xor(smax, 32));
    const float mn = fmaxf(m_, smax);
    const float al = exp2f(m_ - mn);
    float ps = 0.f;
    #pragma unroll
    for (int a = 0; a < 4; ++a)
      #pragma unroll
      for (int r = 0; r < 4; ++r) {
        const float p = exp2f(sc[a][r] - mn);
        sc[a][r] = p;
        ps += p;
      }
    ps += __shfl_xor(ps, 16);
    ps += __shfl_xor(ps, 32);
    l_ = l_ * al + ps;
    m_ = mn;
    #pragma unroll
    for (int t = 0; t < 4; ++t)
      #pragma unroll
      for (int r = 0; r < 4; ++r) oacc[t][r] *= al;

    #pragma unroll
    for (int a = 0; a < 4; ++a)
      #pragma unroll
      for (int j = 0; j < 2; ++j) {
        bf16x2 w;
        w[0] = (bf16_t)sc[a][2 * j];
        w[1] = (bf16_t)sc[a][2 * j + 1];
        const int off = a * 16 + 4 * kgp + 2 * j;
        *(bf16x2*)&p_lds[wid][fr * 64 + (((off >> 3) ^ (fr & 7)) << 3) + (off & 7)] = w;
      }
    const bf16x8 pa0 = *(const bf16x8*)&p_lds[wid][swz8(fr, kgp)];
    const bf16x8 pa1 = *(const bf16x8*)&p_lds[wid][swz8(fr, 4 + kgp)];

    #pragma unroll
    for (int t = 0; t < 4; ++t) {
      const bf16x8 vb0 = *(const bf16x8*)&vt_lds[swz8(t * 16 + fr, kgp)];
      const bf16x8 vb1 = *(const bf16x8*)&vt_lds[swz8(t * 16 + fr, 4 + kgp)];
      oacc[t] = __builtin_amdgcn_mfma_f32_16x16x32_bf16(vb0, pa0, oacc[t], 0, 0, 0);
      oacc[t] = __builtin_amdgcn_mfma_f32_16x16x32_bf16(vb1, pa1, oacc[t], 0, 0, 0);
    }

    if (more) {
      __syncthreads();
      *(bf16x8*)&k_lds[swz8(srow, sc4)]      = nk0;
      *(bf16x8*)&k_lds[swz8(srow, 4 + sc4)]  = nk1;
      *(bf16x8*)&vt_lds[swz8(srow, sc4)]     = nv0;
      *(bf16x8*)&vt_lds[swz8(srow, 4 + sc4)] = nv1;
      __syncthreads();
    }
  }

  const float inv = 1.0f / l_;
  #pragma unroll
  for (int t = 0; t < 4; ++t) {
    bf16x4 o4;
    #pragma unroll
    for (int r = 0; r < 4; ++r) o4[r] = (bf16_t)(oacc[t][r] * inv);
    *(bf16x4*)&ao[(size_t)(q0 + fr) * 2048 + h * 64 + t * 16 + 4 * kgp] = o4;
  }
}

// ---------------- launcher ----------------
extern "C" void kernel_launch(void* const* d_in, const int* in_sizes, int n_in,
                              void* d_out, int out_size, void* d_ws, size_t ws_size,
                              hipStream_t stream) {
  const float* Q  = (const float*)d_in[0];
  const float* K  = (const float*)d_in[1];
  const float* V  = (const float*)d_in[2];
  const int*   am = (const int*)d_in[3];
  const float* Wq = (const float*)d_in[4];
  const float* Wk = (const float*)d_in[5];
  const float* Wv = (const float*)d_in[6];
  const float* Wo = (const float*)d_in[7];
  const float* bo = (const float*)d_in[8];
  float* out = (float*)d_out;

  const int S = 2048, D = 2048;
  char* w = (char*)d_ws;
  const size_t MB = 1u << 20;
  bf16_t* WqT = (bf16_t*)(w + 0 * MB);   // [D][D]
  bf16_t* WoT = (bf16_t*)(w + 8 * MB);   // [D][D]
  bf16_t* WkT = (bf16_t*)(w + 16 * MB);  // [KV][D]
  bf16_t* WvT = (bf16_t*)(w + 18 * MB);
  bf16_t* qh  = (bf16_t*)(w + 20 * MB);  // [32][S][64]
  bf16_t* kgr = (bf16_t*)(w + 28 * MB);  // [8][S][64]
  bf16_t* vtg = (bf16_t*)(w + 30 * MB);  // [8][64][S]
  bf16_t* ao  = (bf16_t*)(w + 32 * MB);  // [S][D]
  bf16_t* Qb  = (bf16_t*)(w + 40 * MB);  // [S][D] bf16
  bf16_t* Kb  = (bf16_t*)(w + 48 * MB);
  bf16_t* Vb  = (bf16_t*)(w + 56 * MB);
  float*  cs  = (float*)(w + 64 * MB);   // [S][32]
  float*  sn  = (float*)(w + 64 * MB + 256 * 1024);

  rope_table_k<<<256, 256, 0, stream>>>(cs, sn, S);
  cast3_k<<<6144, 256, 0, stream>>>(Q, K, V, Qb, Kb, Vb);
  transpose4_k<<<dim3(160, 64), dim3(32, 8), 0, stream>>>(Wq, Wk, Wv, Wo, WqT, WkT, WvT, WoT);

  // fused Q+K+V projections: 768 blocks (64x128 tiles), global_load_lds staging
  gemm_glds_k<0><<<768, 256, 0, stream>>>(Qb, Kb, Vb, WqT, WkT, WvT, D,
                                          cs, sn, qh, kgr, vtg, nullptr, nullptr, S);

  attn_k<<<dim3(32, 32), 256, 0, stream>>>(qh, kgr, vtg, am, ao, S);

  // O-proj: 512 blocks (64x128 tiles), global_load_lds staging
  gemm_glds_k<1><<<512, 256, 0, stream>>>(ao, nullptr, nullptr, WoT, nullptr, nullptr,
                                          D, nullptr, nullptr, nullptr, nullptr, nullptr,
                                          out, bo, S);
}

// Round 11
// 151.992 us; speedup vs baseline: 1.0905x; 1.0102x over previous
//
#include <hip/hip_runtime.h>

typedef __bf16 bf16_t;
typedef __bf16 bf16x8 __attribute__((ext_vector_type(8)));
typedef __bf16 bf16x4 __attribute__((ext_vector_type(4)));
typedef __bf16 bf16x2 __attribute__((ext_vector_type(2)));
typedef float  f32x4  __attribute__((ext_vector_type(4)));

#define LOG2E 1.44269504088896340736f

// global -> LDS direct (width 16B). LDS dest is wave-uniform base + lane*16.
#define GLDS(gp, lp)                                                           \
  __builtin_amdgcn_global_load_lds(                                            \
      (const __attribute__((address_space(1))) void*)(gp),                     \
      (__attribute__((address_space(3))) void*)(lp), 16, 0, 0)

// ---------------- RoPE table: cos/sin [S][32] ----------------
__global__ __launch_bounds__(256) void rope_table_k(float* __restrict__ cs,
                                                    float* __restrict__ sn, int S) {
  int i = blockIdx.x * 256 + threadIdx.x;
  if (i >= S * 32) return;
  int s = i >> 5, j = i & 31;
  float theta = powf(10000.0f, -(float)j * (1.0f / 32.0f));
  float a = (float)s * theta;
  cs[i] = cosf(a);
  sn[i] = sinf(a);
}

// ---------------- fused f32 -> bf16 cast of Q,K,V ----------------
__global__ __launch_bounds__(256) void cast3_k(const float* __restrict__ A,
                                               const float* __restrict__ B,
                                               const float* __restrict__ C,
                                               bf16_t* __restrict__ oa,
                                               bf16_t* __restrict__ ob,
                                               bf16_t* __restrict__ oc) {
  const int b = blockIdx.x;
  const float* in; bf16_t* out;
  if (b < 2048) { in = A; out = oa; }
  else if (b < 4096) { in = B; out = ob; }
  else { in = C; out = oc; }
  const int j = (b & 2047) * 256 + threadIdx.x;
  const float4 v0 = *(const float4*)&in[(size_t)j * 8];
  const float4 v1 = *(const float4*)&in[(size_t)j * 8 + 4];
  bf16x8 o;
  o[0]=(bf16_t)v0.x; o[1]=(bf16_t)v0.y; o[2]=(bf16_t)v0.z; o[3]=(bf16_t)v0.w;
  o[4]=(bf16_t)v1.x; o[5]=(bf16_t)v1.y; o[6]=(bf16_t)v1.z; o[7]=(bf16_t)v1.w;
  *(bf16x8*)&out[(size_t)j * 8] = o;
}

// ---------------- fused 4x weight transpose f32(RxC) -> bf16(CxR), R=2048 ----------------
__global__ void transpose4_k(const float* __restrict__ Wq, const float* __restrict__ Wk,
                             const float* __restrict__ Wv, const float* __restrict__ Wo,
                             bf16_t* __restrict__ WqT, bf16_t* __restrict__ WkT,
                             bf16_t* __restrict__ WvT, bf16_t* __restrict__ WoT) {
  __shared__ float tile[32][33];
  const int bx = blockIdx.x;
  const float* in; bf16_t* out; int C, cbl;
  if (bx < 64)      { in = Wq; out = WqT; C = 2048; cbl = bx; }
  else if (bx < 80) { in = Wk; out = WkT; C = 512;  cbl = bx - 64; }
  else if (bx < 96) { in = Wv; out = WvT; C = 512;  cbl = bx - 80; }
  else              { in = Wo; out = WoT; C = 2048; cbl = bx - 96; }
  const int R = 2048;
  int c0 = cbl * 32, r0 = blockIdx.y * 32;
  int tx = threadIdx.x, ty = threadIdx.y;  // (32,8)
  #pragma unroll
  for (int k = 0; k < 32; k += 8)
    tile[ty + k][tx] = in[(size_t)(r0 + ty + k) * C + c0 + tx];
  __syncthreads();
  #pragma unroll
  for (int k = 0; k < 32; k += 8)
    out[(size_t)(c0 + ty + k) * R + r0 + tx] = (bf16_t)tile[tx][ty + k];
}

// XCD chunking (nb divisible by 8) + 4x4 supertile serpentine mapping
__device__ __forceinline__ int xcd_swz(int bid, int nb) {
  const int q = nb >> 3;
  return (bid & 7) * q + (bid >> 3);
}
__device__ __forceinline__ void st_map(int lin, int nstc, int& rb, int& cb) {
  const int stid = lin >> 4, w = lin & 15;
  const int sr = stid / nstc, t = stid - sr * nstc;
  const int sc = (sr & 1) ? (nstc - 1 - t) : t;
  rb = sr * 4 + (w >> 2);
  cb = sc * 4 + (w & 3);
}

// ---------------- GEMM via global_load_lds: tile 64(M)x128(N), BK=64 ----------------
// Linear LDS rows of 64 bf16 (128B); source pre-swizzled by chunk^(row&7); reads
// apply the same XOR -> 2-way bank aliasing (free). 6 load-instr/wave/K-step.
// MODE 0 (QKV, 768 blocks): cb<16 Q->RoPE-scaled qh; cb<20 K->RoPE kgr; else V->vT vtg
// MODE 1 (O-proj, 512 blocks): f32 out + bias
template<int MODE>
__global__ __launch_bounds__(256) void gemm_glds_k(
    const bf16_t* __restrict__ Aq, const bf16_t* __restrict__ Ak, const bf16_t* __restrict__ Av,
    const bf16_t* __restrict__ Bq, const bf16_t* __restrict__ Bk, const bf16_t* __restrict__ Bv,
    const int K, const float* __restrict__ cs, const float* __restrict__ sn,
    bf16_t* __restrict__ oq, bf16_t* __restrict__ okg, bf16_t* __restrict__ ovt,
    float* __restrict__ ofp, const float* __restrict__ bias, const int S) {
  __shared__ bf16_t a_lds[64 * 64];    // 8 KB, linear
  __shared__ bf16_t b_lds[128 * 64];   // 16 KB, linear
  const int tid = threadIdx.x, wid = tid >> 6, lane = tid & 63;
  const int fr = lane & 15, kg = lane >> 4;

  constexpr int NB   = (MODE == 0) ? 768 : 512;
  constexpr int NSTC = (MODE == 0) ? 6 : 4;
  const int lin = xcd_swz(blockIdx.x, NB);
  int rb, cb; st_map(lin, NSTC, rb, cb);
  const bf16_t* Ap; const bf16_t* Bp; int emode, col0;
  if (MODE == 1)    { Ap = Aq; Bp = Bq; emode = 3; col0 = cb * 128; }
  else if (cb < 16) { Ap = Aq; Bp = Bq; emode = 0; col0 = cb * 128; }
  else if (cb < 20) { Ap = Ak; Bp = Bk; emode = 1; col0 = (cb - 16) * 128; }
  else              { Ap = Av; Bp = Bv; emode = 2; col0 = (cb - 20) * 128; }
  const int row0 = rb * 64;
  const int wr = (wid >> 1) * 32, wc = (wid & 1) * 64;

  f32x4 acc[2][4];
  #pragma unroll
  for (int i = 0; i < 2; ++i)
    #pragma unroll
    for (int j = 0; j < 4; ++j)
      acc[i][j] = (f32x4){0.f, 0.f, 0.f, 0.f};

  // staging geometry: each wave-instr covers 8 rows x 128B contiguous LDS.
  // lane l -> row sub*8 + (l>>3), LDS chunk l&7; source chunk (l&7)^(row&7).
  const int rloc = lane >> 3;                  // 0..7
  const int schunk = ((lane & 7) ^ rloc) * 8;  // pre-swizzled source elem offset
  const bf16_t* gA0 = Ap + (size_t)(row0 + (wid * 2 + 0) * 8 + rloc) * K + schunk;
  const bf16_t* gA1 = Ap + (size_t)(row0 + (wid * 2 + 1) * 8 + rloc) * K + schunk;
  const bf16_t* gB0 = Bp + (size_t)(col0 + (wid * 4 + 0) * 8 + rloc) * K + schunk;
  const bf16_t* gB1 = Bp + (size_t)(col0 + (wid * 4 + 1) * 8 + rloc) * K + schunk;
  const bf16_t* gB2 = Bp + (size_t)(col0 + (wid * 4 + 2) * 8 + rloc) * K + schunk;
  const bf16_t* gB3 = Bp + (size_t)(col0 + (wid * 4 + 3) * 8 + rloc) * K + schunk;
  bf16_t* lA0 = &a_lds[(wid * 2 + 0) * 512];   // wave-uniform LDS bases
  bf16_t* lA1 = &a_lds[(wid * 2 + 1) * 512];
  bf16_t* lB0 = &b_lds[(wid * 4 + 0) * 512];
  bf16_t* lB1 = &b_lds[(wid * 4 + 1) * 512];
  bf16_t* lB2 = &b_lds[(wid * 4 + 2) * 512];
  bf16_t* lB3 = &b_lds[(wid * 4 + 3) * 512];

  for (int kt = 0; kt < K; kt += 64) {
    __syncthreads();                 // all waves done reading previous tile
    GLDS(gA0 + kt, lA0);
    GLDS(gA1 + kt, lA1);
    GLDS(gB0 + kt, lB0);
    GLDS(gB1 + kt, lB1);
    GLDS(gB2 + kt, lB2);
    GLDS(gB3 + kt, lB3);
    __syncthreads();                 // compiler drains vmcnt(0) before barrier
    #pragma unroll
    for (int ks = 0; ks < 2; ++ks) {
      bf16x8 af[2], bfr[4];
      #pragma unroll
      for (int mi = 0; mi < 2; ++mi) {
        const int r = wr + mi * 16 + fr;
        af[mi] = *(const bf16x8*)&a_lds[r * 64 + (((ks * 4 + kg) ^ (fr & 7)) * 8)];
      }
      #pragma unroll
      for (int ni = 0; ni < 4; ++ni) {
        const int r = wc + ni * 16 + fr;
        bfr[ni] = *(const bf16x8*)&b_lds[r * 64 + (((ks * 4 + kg) ^ (fr & 7)) * 8)];
      }
      #pragma unroll
      for (int mi = 0; mi < 2; ++mi)
        #pragma unroll
        for (int ni = 0; ni < 4; ++ni)
          acc[mi][ni] = __builtin_amdgcn_mfma_f32_16x16x32_bf16(af[mi], bfr[ni], acc[mi][ni], 0, 0, 0);
    }
  }

  #pragma unroll
  for (int mi = 0; mi < 2; ++mi) {
    #pragma unroll
    for (int ni = 0; ni < 4; ++ni) {
      #pragma unroll
      for (int r = 0; r < 4; ++r) {
        const int grow = row0 + wr + mi * 16 + kg * 4 + r;  // C row = 4*(lane>>4)+reg
        const int gcol = col0 + wc + ni * 16 + fr;          // C col = lane&15
        float v = acc[mi][ni][r];
        if (emode == 3) {
          ofp[(size_t)grow * 2048 + gcol] = v + bias[gcol];
        } else if (emode == 2) {
          const int gi = gcol >> 6, d = gcol & 63;
          ovt[((size_t)gi * 64 + d) * S + grow] = (bf16_t)v;
        } else {
          const float pv = __shfl_xor(v, 1);  // RoPE partner (d^1), same row
          const int d = gcol & 63, p = d >> 1, hh = gcol >> 6;
          const float c = cs[grow * 32 + p], s = sn[grow * 32 + p];
          float o = (d & 1) ? fmaf(pv, s, v * c) : fmaf(-pv, s, v * c);
          if (emode == 0) {
            o *= 0.125f * LOG2E;  // fold 1/sqrt(64) and log2(e) into q
            oq[((size_t)hh * S + grow) * 64 + d] = (bf16_t)o;
          } else {
            okg[((size_t)hh * S + grow) * 64 + d] = (bf16_t)o;
          }
        }
      }
    }
  }
}

// XOR-swizzled LDS index (T2): row stride 64 bf16 (128B), 16B chunk c^(row&7).
__device__ __forceinline__ int swz8(int r, int c) { return r * 64 + (((c) ^ (r & 7)) << 3); }

// ---------------- flash attention v4: v3 + defer-max (T13) + b64 P-pack + max3 trees ----
__global__ __launch_bounds__(256) void attn_k(
    const bf16_t* __restrict__ qh,   // [32][S][64], pre-scaled by 0.125*log2e
    const bf16_t* __restrict__ kgr,  // [8][S][64]
    const bf16_t* __restrict__ vtg,  // [8][64][S]
    const int* __restrict__ amask,   // [S]
    bf16_t* __restrict__ ao,         // [S][2048]
    const int S) {
  __shared__ bf16_t k_lds[64 * 64];
  __shared__ bf16_t vt_lds[64 * 64];
  __shared__ bf16_t p_lds[4][16 * 64];
  const int tid = threadIdx.x, wid = tid >> 6, lane = tid & 63;
  const int fr = lane & 15, kgp = lane >> 4;
  const int h = blockIdx.x, g = h >> 2;
  const int qb = 31 - blockIdx.y;      // LPT: heavy blocks first in dispatch order
  const int q0 = qb * 64 + wid * 16;
  const int qg = q0 + fr;

  const bf16_t* qbase = qh + ((size_t)h * S + q0 + fr) * 64;
  const bf16x8 qf0 = *(const bf16x8*)&qbase[kgp * 8];
  const bf16x8 qf1 = *(const bf16x8*)&qbase[32 + kgp * 8];

  f32x4 oacc[4];
  #pragma unroll
  for (int t = 0; t < 4; ++t) oacc[t] = (f32x4){0.f, 0.f, 0.f, 0.f};
  float m_ = -1e30f, l_ = 0.f;

  const int srow = tid >> 2, sc4 = tid & 3;
  const bf16_t* kbase = kgr + (size_t)g * S * 64;
  const bf16_t* vbase = vtg + (size_t)g * 64 * S;
  const int cmax = qb + 1;

  bf16x8 nk0 = *(const bf16x8*)&kbase[(size_t)srow * 64 + sc4 * 8];
  bf16x8 nk1 = *(const bf16x8*)&kbase[(size_t)srow * 64 + 32 + sc4 * 8];
  bf16x8 nv0 = *(const bf16x8*)&vbase[(size_t)srow * S + sc4 * 8];
  bf16x8 nv1 = *(const bf16x8*)&vbase[(size_t)srow * S + 32 + sc4 * 8];
  int mvc = amask[lane];
  *(bf16x8*)&k_lds[swz8(srow, sc4)]      = nk0;
  *(bf16x8*)&k_lds[swz8(srow, 4 + sc4)]  = nk1;
  *(bf16x8*)&vt_lds[swz8(srow, sc4)]     = nv0;
  *(bf16x8*)&vt_lds[swz8(srow, 4 + sc4)] = nv1;
  __syncthreads();

  for (int c = 0; c < cmax; ++c) {
    const int kc0 = c * 64;
    const unsigned long long pm = __ballot(mvc == 0);
    const bool more = (c + 1 < cmax);
    if (more) {  // issue-early prefetch (written after compute)
      const int kc1 = kc0 + 64;
      nk0 = *(const bf16x8*)&kbase[(size_t)(kc1 + srow) * 64 + sc4 * 8];
      nk1 = *(const bf16x8*)&kbase[(size_t)(kc1 + srow) * 64 + 32 + sc4 * 8];
      nv0 = *(const bf16x8*)&vbase[(size_t)srow * S + kc1 + sc4 * 8];
      nv1 = *(const bf16x8*)&vbase[(size_t)srow * S + kc1 + 32 + sc4 * 8];
      mvc = amask[kc1 + lane];
    }

    f32x4 sc[4];
    #pragma unroll
    for (int a = 0; a < 4; ++a) {
      const bf16x8 ka0 = *(const bf16x8*)&k_lds[swz8(a * 16 + fr, kgp)];
      const bf16x8 ka1 = *(const bf16x8*)&k_lds[swz8(a * 16 + fr, 4 + kgp)];
      f32x4 z = (f32x4){0.f, 0.f, 0.f, 0.f};
      z = __builtin_amdgcn_mfma_f32_16x16x32_bf16(ka0, qf0, z, 0, 0, 0);
      z = __builtin_amdgcn_mfma_f32_16x16x32_bf16(ka1, qf1, z, 0, 0, 0);
      sc[a] = z;
    }

    if (c == qb) {  // causal: only the diagonal chunk can cross
      #pragma unroll
      for (int a = 0; a < 4; ++a)
        #pragma unroll
        for (int r = 0; r < 4; ++r) {
          const int kl = a * 16 + 4 * kgp + r;
          if (kc0 + kl > qg) sc[a][r] = -1e30f;
        }
    }
    if (pm) {       // pad mask: all-ones input -> skipped (wave-uniform)
      #pragma unroll
      for (int a = 0; a < 4; ++a)
        #pragma unroll
        for (int r = 0; r < 4; ++r) {
          const int kl = a * 16 + 4 * kgp + r;
          if ((pm >> kl) & 1) sc[a][r] = -1e30f;
        }
    }

    // chunk max: pairwise trees (max3-fusable) + 2 shfl
    float t0 = fmaxf(fmaxf(sc[0][0], sc[0][1]), fmaxf(sc[0][2], sc[0][3]));
    float t1 = fmaxf(fmaxf(sc[1][0], sc[1][1]), fmaxf(sc[1][2], sc[1][3]));
    float t2 = fmaxf(fmaxf(sc[2][0], sc[2][1]), fmaxf(sc[2][2], sc[2][3]));
    float t3 = fmaxf(fmaxf(sc[3][0], sc[3][1]), fmaxf(sc[3][2], sc[3][3]));
    float smax = fmaxf(fmaxf(t0, t1), fmaxf(t2, t3));
    smax = fmaxf(smax, __shfl_xor(smax, 16));
    smax = fmaxf(smax, __shfl_xor(smax, 32));

    // defer-max (T13): skip rescale while the running max grows < 8 (log2 units);
    // P then bounded by 2^8 -- fine in bf16, l_/oacc have f32 headroom.
    const bool rescale = !__all(smax <= m_ + 8.0f);
    if (rescale) {
      const float mn = fmaxf(m_, smax);
      const float al = exp2f(m_ - mn);
      m_ = mn;
      #pragma unroll
      for (int t = 0; t < 4; ++t)
        #pragma unroll
        for (int r = 0; r < 4; ++r) oacc[t][r] *= al;
      l_ *= al;
    }

    float ps = 0.f;
    #pragma unroll
    for (int a = 0; a < 4; ++a)
      #pragma unroll
      for (int r = 0; r < 4; ++r) {
        const float p = exp2f(sc[a][r] - m_);
        sc[a][r] = p;
        ps += p;
      }
    ps += __shfl_xor(ps, 16);
    ps += __shfl_xor(ps, 32);
    l_ += ps;

    // P -> LDS: 4 x b64 swizzled writes (4 consecutive bf16 stay in one 8-elem chunk)
    #pragma unroll
    for (int a = 0; a < 4; ++a) {
      bf16x4 w;
      w[0] = (bf16_t)sc[a][0];
      w[1] = (bf16_t)sc[a][1];
      w[2] = (bf16_t)sc[a][2];
      w[3] = (bf16_t)sc[a][3];
      const int off = a * 16 + 4 * kgp;
      *(bf16x4*)&p_lds[wid][fr * 64 + (((off >> 3) ^ (fr & 7)) << 3) + (off & 7)] = w;
    }
    const bf16x8 pa0 = *(const bf16x8*)&p_lds[wid][swz8(fr, kgp)];
    const bf16x8 pa1 = *(const bf16x8*)&p_lds[wid][swz8(fr, 4 + kgp)];

    #pragma unroll
    for (int t = 0; t < 4; ++t) {
      const bf16x8 vb0 = *(const bf16x8*)&vt_lds[swz8(t * 16 + fr, kgp)];
      const bf16x8 vb1 = *(const bf16x8*)&vt_lds[swz8(t * 16 + fr, 4 + kgp)];
      oacc[t] = __builtin_amdgcn_mfma_f32_16x16x32_bf16(vb0, pa0, oacc[t], 0, 0, 0);
      oacc[t] = __builtin_amdgcn_mfma_f32_16x16x32_bf16(vb1, pa1, oacc[t], 0, 0, 0);
    }

    if (more) {
      __syncthreads();
      *(bf16x8*)&k_lds[swz8(srow, sc4)]      = nk0;
      *(bf16x8*)&k_lds[swz8(srow, 4 + sc4)]  = nk1;
      *(bf16x8*)&vt_lds[swz8(srow, sc4)]     = nv0;
      *(bf16x8*)&vt_lds[swz8(srow, 4 + sc4)] = nv1;
      __syncthreads();
    }
  }

  const float inv = 1.0f / l_;
  #pragma unroll
  for (int t = 0; t < 4; ++t) {
    bf16x4 o4;
    #pragma unroll
    for (int r = 0; r < 4; ++r) o4[r] = (bf16_t)(oacc[t][r] * inv);
    *(bf16x4*)&ao[(size_t)(q0 + fr) * 2048 + h * 64 + t * 16 + 4 * kgp] = o4;
  }
}

// ---------------- launcher ----------------
extern "C" void kernel_launch(void* const* d_in, const int* in_sizes, int n_in,
                              void* d_out, int out_size, void* d_ws, size_t ws_size,
                              hipStream_t stream) {
  const float* Q  = (const float*)d_in[0];
  const float* K  = (const float*)d_in[1];
  const float* V  = (const float*)d_in[2];
  const int*   am = (const int*)d_in[3];
  const float* Wq = (const float*)d_in[4];
  const float* Wk = (const float*)d_in[5];
  const float* Wv = (const float*)d_in[6];
  const float* Wo = (const float*)d_in[7];
  const float* bo = (const float*)d_in[8];
  float* out = (float*)d_out;

  const int S = 2048, D = 2048;
  char* w = (char*)d_ws;
  const size_t MB = 1u << 20;
  bf16_t* WqT = (bf16_t*)(w + 0 * MB);   // [D][D]
  bf16_t* WoT = (bf16_t*)(w + 8 * MB);   // [D][D]
  bf16_t* WkT = (bf16_t*)(w + 16 * MB);  // [KV][D]
  bf16_t* WvT = (bf16_t*)(w + 18 * MB);
  bf16_t* qh  = (bf16_t*)(w + 20 * MB);  // [32][S][64]
  bf16_t* kgr = (bf16_t*)(w + 28 * MB);  // [8][S][64]
  bf16_t* vtg = (bf16_t*)(w + 30 * MB);  // [8][64][S]
  bf16_t* ao  = (bf16_t*)(w + 32 * MB);  // [S][D]
  bf16_t* Qb  = (bf16_t*)(w + 40 * MB);  // [S][D] bf16
  bf16_t* Kb  = (bf16_t*)(w + 48 * MB);
  bf16_t* Vb  = (bf16_t*)(w + 56 * MB);
  float*  cs  = (float*)(w + 64 * MB);   // [S][32]
  float*  sn  = (float*)(w + 64 * MB + 256 * 1024);

  rope_table_k<<<256, 256, 0, stream>>>(cs, sn, S);
  cast3_k<<<6144, 256, 0, stream>>>(Q, K, V, Qb, Kb, Vb);
  transpose4_k<<<dim3(160, 64), dim3(32, 8), 0, stream>>>(Wq, Wk, Wv, Wo, WqT, WkT, WvT, WoT);

  // fused Q+K+V projections: 768 blocks (64x128 tiles), global_load_lds staging
  gemm_glds_k<0><<<768, 256, 0, stream>>>(Qb, Kb, Vb, WqT, WkT, WvT, D,
                                          cs, sn, qh, kgr, vtg, nullptr, nullptr, S);

  attn_k<<<dim3(32, 32), 256, 0, stream>>>(qh, kgr, vtg, am, ao, S);

  // O-proj: 512 blocks (64x128 tiles), global_load_lds staging
  gemm_glds_k<1><<<512, 256, 0, stream>>>(ao, nullptr, nullptr, WoT, nullptr, nullptr,
                                          D, nullptr, nullptr, nullptr, nullptr, nullptr,
                                          out, bo, S);
}